// Round 9
// baseline (1971.480 us; speedup 1.0000x reference)
//
#include <hip/hip_runtime.h>
#include <math.h>

namespace {

constexpr int DD = 128;
constexpr int DM = 127;
constexpr int D3 = DD * DD * DD;

struct Consts {
  float kn, ps, eta, dtpm, grav;
  float lo_hi;   // 1.5*PS
  float hi_th;   // D*CELL - 0.5*PS - CELL
  float dcell;   // D*CELL
  float cell;    // CELL
  float hps;     // 0.5*PS
  float ps2;     // PS*PS
  float nknps;   // -(KN*PS)
};

__device__ inline float bforce(float p, float v, float mkv, const Consts& c) {
  float lo = ((p > c.ps) && (p < c.lo_hi)) ? mkv : 0.0f;
  float hi = (p > c.hi_th) ? mkv : 0.0f;
  float t = ((p - c.dcell) + c.cell) + c.hps;   // mirrors ref op order
  return c.kn * lo * (c.lo_hi - p) - c.kn * hi * t - c.eta * v * lo - c.eta * v * hi;
}

__device__ __forceinline__ float f4c(const float4& v, int u) {
  return u == 0 ? v.x : (u == 1 ? v.y : (u == 2 ? v.z : v.w));
}

// Scalar fallback (R=2, full 125-offset correctness path; rarely taken).
template <int R>
__device__ void collide(int x, int y, int z,
                        const float* __restrict__ xg, const float* __restrict__ yg,
                        const float* __restrict__ zg,
                        const float* __restrict__ v0x, const float* __restrict__ v0y,
                        const float* __restrict__ v0z,
                        const float* __restrict__ v1x, const float* __restrict__ v1y,
                        const float* __restrict__ v1z,
                        float xn, float yn, float zn,
                        float vxn, float vyn, float vzn,
                        float& fx, float& fy, float& fz, const Consts& c) {
  int xw[2 * R + 1];
#pragma unroll
  for (int ox = -R; ox <= R; ++ox) xw[ox + R] = (x + ox) & DM;

  for (int oz = -R; oz <= R; ++oz) {
    const int zr = (z + oz) & DM;
    for (int oy = -R; oy <= R; ++oy) {
      const int yr = (y + oy) & DM;
      const int rb = (zr * DD + yr) * DD;
#pragma unroll
      for (int m = 0; m < 2; ++m) {
        const float* __restrict__ PX = xg + m * D3 + rb;
        const float* __restrict__ PY = yg + m * D3 + rb;
        const float* __restrict__ PZ = zg + m * D3 + rb;
        const float* __restrict__ VX = (m == 0 ? v0x : v1x) + rb;
        const float* __restrict__ VY = (m == 0 ? v0y : v1y) + rb;
        const float* __restrict__ VZ = (m == 0 ? v0z : v1z) + rb;
#pragma unroll
        for (int ox = -R; ox <= R; ++ox) {
          const int xi = xw[ox + R];
          float dx = xn - PX[xi];
          float dy = yn - PY[xi];
          float dz = zn - PZ[xi];
          float d2 = fmaf(dx, dx, fmaf(dy, dy, dz * dz));
          float d2c = fmaxf(d2, 1e-12f);
          float r = __builtin_amdgcn_rsqf(d2c);
          float dist = d2c * r;
          float inv = fminf(r, 1.0e4f);
          float dvx = vxn - VX[xi];
          float dvy = vyn - VY[xi];
          float dvz = vzn - VZ[xi];
          float dvn = fmaf(dvx, dx, fmaf(dvy, dy, dvz * dz)) * inv;
          float coef = (dist < c.ps) ? (fmaf(c.kn, dist - c.ps, c.eta * dvn) * inv) : 0.0f;
          fx = fmaf(coef, dx, fx);
          fy = fmaf(coef, dy, fy);
          fz = fmaf(coef, dz, fz);
        }
      }
    }
  }
}

__global__ void __launch_bounds__(256)
checker(const float* __restrict__ xg, const float* __restrict__ yg,
        const float* __restrict__ zg, unsigned* flag, float cell) {
  int i = blockIdx.x * 256 + threadIdx.x;   // i in [0, 2*D3)
  int ix = i & DM;
  int iy = (i >> 7) & DM;
  int iz = (i >> 14) & DM;
  float jx = xg[i] - ix * cell;
  float jy = yg[i] - iy * cell;
  float jz = zg[i] - iz * cell;
  const float lo = -1e-5f, hi = cell + 1e-5f;
  bool bad = (jx < lo) | (jx > hi) | (jy < lo) | (jy > hi) | (jz < lo) | (jz > hi);
  if (bad) atomicOr(flag, 1u);
}

// 8 cells/thread (4x*2y); per layer a 12-row stream (4 y-rows x 3 z-planes)
// with 3-buffer rotating prefetch (each row load covered by ~2 row-computes,
// ~600-1200cy >= L3-hit latency). Two static-pointer layer loops. 64-thread
// wgs (grid 4096) kill the wg-quantization tail at 3 waves/SIMD. Trimmed math
// (R5/R6-validated): coef = KN - KN*PS*inv + ETA*dvnr*inv^2, gate d2 < PS^2.
__global__ void __launch_bounds__(64)
dem_pass(int n,
         const float* __restrict__ xg, const float* __restrict__ yg,
         const float* __restrict__ zg,
         const float* __restrict__ v0x, const float* __restrict__ v0y,
         const float* __restrict__ v0z,
         const float* __restrict__ v1x, const float* __restrict__ v1y,
         const float* __restrict__ v1z,
         const float* __restrict__ vnx, const float* __restrict__ vny,
         const float* __restrict__ vnz,
         const float* __restrict__ maskn,
         float* __restrict__ outx, float* __restrict__ outy, float* __restrict__ outz,
         const unsigned* __restrict__ flag, Consts cc) {
  const int t = threadIdx.x;
  const int tx = t & 31;
  const int th = t >> 5;                       // 0..1
  // bijective chunked XCD swizzle: 4096 wgs, 8 XCDs, 512 wgs/XCD
  const int wg = blockIdx.x;
  const int id = ((wg & 7) << 9) | (wg >> 3);
  const int z = id >> 5;                       // 0..127
  const int y0 = ((id & 31) << 2) | (th << 1); // even rows; thread owns y0, y0+1
  const int x0 = tx << 2;
  const int idx0 = (z * DD + y0) * DD + x0;
  const int idx1 = idx0 + DD;
  const int nn = n * D3;

  float px0[4], py0[4], pz0[4], vx0[4], vy0[4], vz0[4];
  float px1[4], py1[4], pz1[4], vx1[4], vy1[4], vz1[4];
  {
    float4 a;
    a = *(const float4*)(xg + nn + idx0);  px0[0]=a.x; px0[1]=a.y; px0[2]=a.z; px0[3]=a.w;
    a = *(const float4*)(yg + nn + idx0);  py0[0]=a.x; py0[1]=a.y; py0[2]=a.z; py0[3]=a.w;
    a = *(const float4*)(zg + nn + idx0);  pz0[0]=a.x; pz0[1]=a.y; pz0[2]=a.z; pz0[3]=a.w;
    a = *(const float4*)(vnx + idx0);      vx0[0]=a.x; vx0[1]=a.y; vx0[2]=a.z; vx0[3]=a.w;
    a = *(const float4*)(vny + idx0);      vy0[0]=a.x; vy0[1]=a.y; vy0[2]=a.z; vy0[3]=a.w;
    a = *(const float4*)(vnz + idx0);      vz0[0]=a.x; vz0[1]=a.y; vz0[2]=a.z; vz0[3]=a.w;
    a = *(const float4*)(xg + nn + idx1);  px1[0]=a.x; px1[1]=a.y; px1[2]=a.z; px1[3]=a.w;
    a = *(const float4*)(yg + nn + idx1);  py1[0]=a.x; py1[1]=a.y; py1[2]=a.z; py1[3]=a.w;
    a = *(const float4*)(zg + nn + idx1);  pz1[0]=a.x; pz1[1]=a.y; pz1[2]=a.z; pz1[3]=a.w;
    a = *(const float4*)(vnx + idx1);      vx1[0]=a.x; vx1[1]=a.y; vx1[2]=a.z; vx1[3]=a.w;
    a = *(const float4*)(vny + idx1);      vy1[0]=a.x; vy1[1]=a.y; vy1[2]=a.z; vy1[3]=a.w;
    a = *(const float4*)(vnz + idx1);      vz1[0]=a.x; vz1[1]=a.y; vz1[2]=a.z; vz1[3]=a.w;
  }

  float fx0[4] = {0.f,0.f,0.f,0.f}, fy0[4] = {0.f,0.f,0.f,0.f}, fz0[4] = {0.f,0.f,0.f,0.f};
  float fx1[4] = {0.f,0.f,0.f,0.f}, fy1[4] = {0.f,0.f,0.f,0.f}, fz1[4] = {0.f,0.f,0.f,0.f};

  if (*flag == 0u) {
    const int laneL = (t & 32) | ((tx + 31) & 31);
    const int laneR = (t & 32) | ((tx + 1) & 31);
    const float KNc = cc.kn, PS2 = cc.ps2, NKNPS = cc.nknps, ETAc = cc.eta;

    auto interact4 = [&](const float4 (&Rf)[6], const float (&lo)[6], const float (&hi)[6],
                         const float (&px)[4], const float (&py)[4], const float (&pz)[4],
                         const float (&vx)[4], const float (&vy)[4], const float (&vz)[4],
                         float (&fx)[4], float (&fy)[4], float (&fz)[4]) {
#pragma unroll
      for (int i = 0; i < 4; ++i) {
#pragma unroll
        for (int ox = 0; ox < 3; ++ox) {
          const int u = i + ox - 1;   // -1..4, compile-time after unroll
          const float wx  = (u < 0) ? lo[0] : ((u > 3) ? hi[0] : f4c(Rf[0], u));
          const float wy  = (u < 0) ? lo[1] : ((u > 3) ? hi[1] : f4c(Rf[1], u));
          const float wz  = (u < 0) ? lo[2] : ((u > 3) ? hi[2] : f4c(Rf[2], u));
          const float wvx = (u < 0) ? lo[3] : ((u > 3) ? hi[3] : f4c(Rf[3], u));
          const float wvy = (u < 0) ? lo[4] : ((u > 3) ? hi[4] : f4c(Rf[4], u));
          const float wvz = (u < 0) ? lo[5] : ((u > 3) ? hi[5] : f4c(Rf[5], u));
          float dx = px[i] - wx;
          float dy = py[i] - wy;
          float dz = pz[i] - wz;
          float d2 = fmaf(dx, dx, fmaf(dy, dy, dz * dz));
          float r = __builtin_amdgcn_rsqf(d2);     // d2=0 -> inf -> clamped below
          float inv = fminf(r, 1.0e4f);            // = 1/max(dist, 1e-4)
          float inv2 = inv * inv;
          float dvx = vx[i] - wvx;
          float dvy = vy[i] - wvy;
          float dvz = vz[i] - wvz;
          float dvnr = fmaf(dvx, dx, fmaf(dvy, dy, dvz * dz));
          float coef = fmaf(ETAc, dvnr * inv2, fmaf(NKNPS, inv, KNc));
          coef = (d2 < PS2) ? coef : 0.0f;
          fx[i] = fmaf(coef, dx, fx[i]);
          fy[i] = fmaf(coef, dy, fy[i]);
          fz[i] = fmaf(coef, dz, fz[i]);
        }
      }
    };

    // row k in [0,12): j = k&3 (y-row y0+j-1), oz = k>>2 (plane z+oz-1).
    auto compute_row = [&](const float4 (&Rf)[6], int j) {
      float lo[6], hi[6];
#pragma unroll
      for (int f = 0; f < 6; ++f) {
        lo[f] = __shfl(Rf[f].w, laneL, 64);
        hi[f] = __shfl(Rf[f].x, laneR, 64);
      }
      if (j != 3) interact4(Rf, lo, hi, px0, py0, pz0, vx0, vy0, vz0, fx0, fy0, fz0);
      if (j != 0) interact4(Rf, lo, hi, px1, py1, pz1, vx1, vy1, vz1, fx1, fy1, fz1);
    };

    auto rowbase = [&](int k) -> int {
      const int zr = (z + (k >> 2) + DM) & DM;
      const int yr = (y0 + (k & 3) + DM) & DM;
      return (zr << 14) + (yr << 7) + x0;
    };

    // One layer: 12-row stream with 3-buffer rotation, depth-2 cover, peeled tail.
    auto run_layer = [&](const float* __restrict__ P0, const float* __restrict__ P1,
                         const float* __restrict__ P2, const float* __restrict__ P3,
                         const float* __restrict__ P4, const float* __restrict__ P5) {
      float4 T0[6], T1[6], T2[6];
      auto ldrow = [&](float4 (&T)[6], int k) {
        const int rb = rowbase(k);
        T[0] = *(const float4*)(P0 + rb);
        T[1] = *(const float4*)(P1 + rb);
        T[2] = *(const float4*)(P2 + rb);
        T[3] = *(const float4*)(P3 + rb);
        T[4] = *(const float4*)(P4 + rb);
        T[5] = *(const float4*)(P5 + rb);
      };
      ldrow(T0, 0);
      ldrow(T1, 1);
#pragma unroll 1
      for (int rr = 0; rr < 9; rr += 3) {
        ldrow(T2, rr + 2); compute_row(T0, rr & 3);
        ldrow(T0, rr + 3); compute_row(T1, (rr + 1) & 3);
        ldrow(T1, rr + 4); compute_row(T2, (rr + 2) & 3);
      }
      // peeled tail rr=9: rows 9,10,11 (no dead prefetch)
      ldrow(T2, 11); compute_row(T0, 1);
      compute_row(T1, 2);
      compute_row(T2, 3);
    };

    run_layer(xg, yg, zg, v0x, v0y, v0z);
    run_layer(xg + D3, yg + D3, zg + D3, v1x, v1y, v1z);
  } else {
#pragma unroll
    for (int i = 0; i < 4; ++i) {
      collide<2>(x0 + i, y0, z, xg, yg, zg, v0x, v0y, v0z, v1x, v1y, v1z,
                 px0[i], py0[i], pz0[i], vx0[i], vy0[i], vz0[i],
                 fx0[i], fy0[i], fz0[i], cc);
      collide<2>(x0 + i, y0 + 1, z, xg, yg, zg, v0x, v0y, v0z, v1x, v1y, v1z,
                 px1[i], py1[i], pz1[i], vx1[i], vy1[i], vz1[i],
                 fx1[i], fy1[i], fz1[i], cc);
    }
  }

  const float4 mk04 = *(const float4*)(maskn + idx0);   // mask loaded late:
  const float4 mk14 = *(const float4*)(maskn + idx1);   // keeps it out of loop liveness
  float4 ox4, oy4, oz4;
#pragma unroll
  for (int i = 0; i < 4; ++i) {
    const float mkv = f4c(mk04, i);
    const float fxb = bforce(px0[i], vx0[i], mkv, cc);
    const float fyb = bforce(py0[i], vy0[i], mkv, cc);
    const float fzb = bforce(pz0[i], vz0[i], mkv, cc);
    const float s = cc.dtpm * mkv;
    (&ox4.x)[i] = vx0[i] + s * (fxb - fx0[i]);
    (&oy4.x)[i] = vy0[i] + s * (fyb - fy0[i]);
    (&oz4.x)[i] = vz0[i] + s * ((cc.grav - fz0[i]) + fzb);
  }
  *(float4*)(outx + idx0) = ox4;
  *(float4*)(outy + idx0) = oy4;
  *(float4*)(outz + idx0) = oz4;
#pragma unroll
  for (int i = 0; i < 4; ++i) {
    const float mkv = f4c(mk14, i);
    const float fxb = bforce(px1[i], vx1[i], mkv, cc);
    const float fyb = bforce(py1[i], vy1[i], mkv, cc);
    const float fzb = bforce(pz1[i], vz1[i], mkv, cc);
    const float s = cc.dtpm * mkv;
    (&ox4.x)[i] = vx1[i] + s * (fxb - fx1[i]);
    (&oy4.x)[i] = vy1[i] + s * (fyb - fy1[i]);
    (&oz4.x)[i] = vz1[i] + s * ((cc.grav - fz1[i]) + fzb);
  }
  *(float4*)(outx + idx1) = ox4;
  *(float4*)(outy + idx1) = oy4;
  *(float4*)(outz + idx1) = oz4;
}

}  // namespace

extern "C" void kernel_launch(void* const* d_in, const int* in_sizes, int n_in,
                              void* d_out, int out_size, void* d_ws, size_t ws_size,
                              hipStream_t stream) {
  const float* xg = (const float*)d_in[0];
  const float* yg = (const float*)d_in[1];
  const float* zg = (const float*)d_in[2];
  const float* vx = (const float*)d_in[3];
  const float* vy = (const float*)d_in[4];
  const float* vz = (const float*)d_in[5];
  const float* mk = (const float*)d_in[6];
  float* out = (float*)d_out;
  unsigned* flag = (unsigned*)d_ws;

  const double PSd = 0.1, CELLd = 0.1, KNd = 6.0e6;
  const double ALPHA = -log(0.5) / 3.141592653589793;
  const double GAMMA = ALPHA / sqrt(ALPHA * ALPHA + 1.0);
  const double PMd = 4.0 / 3.0 * 3.1415 * (0.1 * 0.1 * 0.1) * 2700.0;
  const double ETAd = 2.0 * GAMMA * sqrt(KNd * PMd);

  Consts cc;
  cc.kn = (float)KNd;
  cc.ps = (float)PSd;
  cc.eta = (float)ETAd;
  cc.dtpm = (float)(1e-4 / PMd);
  cc.grav = (float)(-9.8 * PMd);
  cc.lo_hi = (float)(1.5 * PSd);
  cc.hi_th = (float)(DD * CELLd - 0.5 * PSd - CELLd);
  cc.dcell = (float)(DD * CELLd);
  cc.cell = (float)CELLd;
  cc.hps = (float)(0.5 * PSd);
  cc.ps2 = cc.ps * cc.ps;
  cc.nknps = -(cc.kn * cc.ps);

  hipMemsetAsync(d_ws, 0, sizeof(unsigned), stream);
  checker<<<(2 * D3) / 256, 256, 0, stream>>>(xg, yg, zg, flag, cc.cell);

  dim3 blk(64, 1, 1), grd(4096, 1, 1);
  // Pass n=0: neighbor velocities = original inputs (both layers); own = input layer 0.
  dem_pass<<<grd, blk, 0, stream>>>(
      0, xg, yg, zg,
      vx, vy, vz,
      vx + D3, vy + D3, vz + D3,
      vx, vy, vz,
      mk,
      out, out + 2 * D3, out + 4 * D3,
      flag, cc);
  // Pass n=1: m=0 source is the UPDATED layer 0 (just written to out).
  dem_pass<<<grd, blk, 0, stream>>>(
      1, xg, yg, zg,
      out, out + 2 * D3, out + 4 * D3,
      vx + D3, vy + D3, vz + D3,
      vx + D3, vy + D3, vz + D3,
      mk + D3,
      out + D3, out + 3 * D3, out + 5 * D3,
      flag, cc);
}

// Round 10
// 165.518 us; speedup vs baseline: 11.9110x; 11.9110x over previous
//
#include <hip/hip_runtime.h>
#include <math.h>

namespace {

constexpr int DD = 128;
constexpr int DM = 127;
constexpr int D3 = DD * DD * DD;

struct Consts {
  float kn, ps, eta, dtpm, grav;
  float lo_hi;   // 1.5*PS
  float hi_th;   // D*CELL - 0.5*PS - CELL
  float dcell;   // D*CELL
  float cell;    // CELL
  float hps;     // 0.5*PS
  float ps2;     // PS*PS
  float nknps;   // -(KN*PS)
};

__device__ inline float bforce(float p, float v, float mkv, const Consts& c) {
  float lo = ((p > c.ps) && (p < c.lo_hi)) ? mkv : 0.0f;
  float hi = (p > c.hi_th) ? mkv : 0.0f;
  float t = ((p - c.dcell) + c.cell) + c.hps;   // mirrors ref op order
  return c.kn * lo * (c.lo_hi - p) - c.kn * hi * t - c.eta * v * lo - c.eta * v * hi;
}

__device__ __forceinline__ float f4c(const float4& v, int u) {
  return u == 0 ? v.x : (u == 1 ? v.y : (u == 2 ? v.z : v.w));
}

// Scalar fallback (R=2, full 125-offset correctness path; rarely taken).
template <int R>
__device__ void collide(int x, int y, int z,
                        const float* __restrict__ xg, const float* __restrict__ yg,
                        const float* __restrict__ zg,
                        const float* __restrict__ v0x, const float* __restrict__ v0y,
                        const float* __restrict__ v0z,
                        const float* __restrict__ v1x, const float* __restrict__ v1y,
                        const float* __restrict__ v1z,
                        float xn, float yn, float zn,
                        float vxn, float vyn, float vzn,
                        float& fx, float& fy, float& fz, const Consts& c) {
  int xw[2 * R + 1];
#pragma unroll
  for (int ox = -R; ox <= R; ++ox) xw[ox + R] = (x + ox) & DM;

  for (int oz = -R; oz <= R; ++oz) {
    const int zr = (z + oz) & DM;
    for (int oy = -R; oy <= R; ++oy) {
      const int yr = (y + oy) & DM;
      const int rb = (zr * DD + yr) * DD;
#pragma unroll
      for (int m = 0; m < 2; ++m) {
        const float* __restrict__ PX = xg + m * D3 + rb;
        const float* __restrict__ PY = yg + m * D3 + rb;
        const float* __restrict__ PZ = zg + m * D3 + rb;
        const float* __restrict__ VX = (m == 0 ? v0x : v1x) + rb;
        const float* __restrict__ VY = (m == 0 ? v0y : v1y) + rb;
        const float* __restrict__ VZ = (m == 0 ? v0z : v1z) + rb;
#pragma unroll
        for (int ox = -R; ox <= R; ++ox) {
          const int xi = xw[ox + R];
          float dx = xn - PX[xi];
          float dy = yn - PY[xi];
          float dz = zn - PZ[xi];
          float d2 = fmaf(dx, dx, fmaf(dy, dy, dz * dz));
          float d2c = fmaxf(d2, 1e-12f);
          float r = __builtin_amdgcn_rsqf(d2c);
          float dist = d2c * r;
          float inv = fminf(r, 1.0e4f);
          float dvx = vxn - VX[xi];
          float dvy = vyn - VY[xi];
          float dvz = vzn - VZ[xi];
          float dvn = fmaf(dvx, dx, fmaf(dvy, dy, dvz * dz)) * inv;
          float coef = (dist < c.ps) ? (fmaf(c.kn, dist - c.ps, c.eta * dvn) * inv) : 0.0f;
          fx = fmaf(coef, dx, fx);
          fy = fmaf(coef, dy, fy);
          fz = fmaf(coef, dz, fz);
        }
      }
    }
  }
}

__global__ void __launch_bounds__(256)
checker(const float* __restrict__ xg, const float* __restrict__ yg,
        const float* __restrict__ zg, unsigned* flag, float cell) {
  int i = blockIdx.x * 256 + threadIdx.x;   // i in [0, 2*D3)
  int ix = i & DM;
  int iy = (i >> 7) & DM;
  int iz = (i >> 14) & DM;
  float jx = xg[i] - ix * cell;
  float jy = yg[i] - iy * cell;
  float jz = zg[i] - iz * cell;
  const float lo = -1e-5f, hi = cell + 1e-5f;
  bool bad = (jx < lo) | (jx > hi) | (jy < lo) | (jy > hi) | (jz < lo) | (jz > hi);
  if (bad) atomicOr(flag, 1u);
}

// R8 structure (best: VGPR 108, no spill): 8 cells/thread (4x*2y), 12-row
// stream per layer-pair iteration, two named A/B row buffers, depth-1
// pipeline, shfl halos, XCD-chunked swizzle. R10 refinements: (a) interior-
// first interaction order so the 12 ds_bpermute halos get ~300cy of cover
// before first use; (b) mask loaded after the loop (8 fewer live VGPRs).
__global__ void __launch_bounds__(256)
dem_pass(int n,
         const float* __restrict__ xg, const float* __restrict__ yg,
         const float* __restrict__ zg,
         const float* __restrict__ v0x, const float* __restrict__ v0y,
         const float* __restrict__ v0z,
         const float* __restrict__ v1x, const float* __restrict__ v1y,
         const float* __restrict__ v1z,
         const float* __restrict__ vnx, const float* __restrict__ vny,
         const float* __restrict__ vnz,
         const float* __restrict__ maskn,
         float* __restrict__ outx, float* __restrict__ outy, float* __restrict__ outz,
         const unsigned* __restrict__ flag, Consts cc) {
  const int t = threadIdx.x;
  const int tx = t & 31;
  const int ty = t >> 5;                       // 0..7
  // bijective chunked XCD swizzle: 1024 wgs, 8 XCDs, 128 wgs (16 z-slices) each
  const int wg = blockIdx.x;
  const int id = ((wg & 7) << 7) | (wg >> 3);
  const int z = id >> 3;                       // 0..127
  const int y0 = ((id & 7) << 4) | (ty << 1);  // even rows 0..126; thread owns y0, y0+1
  const int x0 = tx << 2;
  const int idx0 = (z * DD + y0) * DD + x0;
  const int idx1 = idx0 + DD;
  const int nn = n * D3;

  float px0[4], py0[4], pz0[4], vx0[4], vy0[4], vz0[4];
  float px1[4], py1[4], pz1[4], vx1[4], vy1[4], vz1[4];
  {
    float4 a;
    a = *(const float4*)(xg + nn + idx0);  px0[0]=a.x; px0[1]=a.y; px0[2]=a.z; px0[3]=a.w;
    a = *(const float4*)(yg + nn + idx0);  py0[0]=a.x; py0[1]=a.y; py0[2]=a.z; py0[3]=a.w;
    a = *(const float4*)(zg + nn + idx0);  pz0[0]=a.x; pz0[1]=a.y; pz0[2]=a.z; pz0[3]=a.w;
    a = *(const float4*)(vnx + idx0);      vx0[0]=a.x; vx0[1]=a.y; vx0[2]=a.z; vx0[3]=a.w;
    a = *(const float4*)(vny + idx0);      vy0[0]=a.x; vy0[1]=a.y; vy0[2]=a.z; vy0[3]=a.w;
    a = *(const float4*)(vnz + idx0);      vz0[0]=a.x; vz0[1]=a.y; vz0[2]=a.z; vz0[3]=a.w;
    a = *(const float4*)(xg + nn + idx1);  px1[0]=a.x; px1[1]=a.y; px1[2]=a.z; px1[3]=a.w;
    a = *(const float4*)(yg + nn + idx1);  py1[0]=a.x; py1[1]=a.y; py1[2]=a.z; py1[3]=a.w;
    a = *(const float4*)(zg + nn + idx1);  pz1[0]=a.x; pz1[1]=a.y; pz1[2]=a.z; pz1[3]=a.w;
    a = *(const float4*)(vnx + idx1);      vx1[0]=a.x; vx1[1]=a.y; vx1[2]=a.z; vx1[3]=a.w;
    a = *(const float4*)(vny + idx1);      vy1[0]=a.x; vy1[1]=a.y; vy1[2]=a.z; vy1[3]=a.w;
    a = *(const float4*)(vnz + idx1);      vz1[0]=a.x; vz1[1]=a.y; vz1[2]=a.z; vz1[3]=a.w;
  }

  float fx0[4] = {0.f,0.f,0.f,0.f}, fy0[4] = {0.f,0.f,0.f,0.f}, fz0[4] = {0.f,0.f,0.f,0.f};
  float fx1[4] = {0.f,0.f,0.f,0.f}, fy1[4] = {0.f,0.f,0.f,0.f}, fz1[4] = {0.f,0.f,0.f,0.f};

  if (*flag == 0u) {
    const int laneL = (t & 32) | ((tx + 31) & 31);
    const int laneR = (t & 32) | ((tx + 1) & 31);
    const float* __restrict__ Q0[6] = {xg, yg, zg, v0x, v0y, v0z};
    const float* __restrict__ Q1[6] = {xg + D3, yg + D3, zg + D3, v1x, v1y, v1z};

    const float KNc = cc.kn, PS2 = cc.ps2, NKNPS = cc.nknps, ETAc = cc.eta;

    auto interact4 = [&](const float4 (&Rf)[6], const float (&lo)[6], const float (&hi)[6],
                         const float (&px)[4], const float (&py)[4], const float (&pz)[4],
                         const float (&vx)[4], const float (&vy)[4], const float (&vz)[4],
                         float (&fx)[4], float (&fy)[4], float (&fz)[4]) {
      // interior-first order: the 2 halo-consuming pairs (0,0)->u=-1 and
      // (3,2)->u=4 run LAST, giving the shfl results ~10 interactions of cover.
      constexpr int ORD[12][2] = {{0,1},{0,2},{1,0},{1,1},{1,2},{2,0},
                                  {2,1},{2,2},{3,0},{3,1},{0,0},{3,2}};
#pragma unroll
      for (int q = 0; q < 12; ++q) {
        const int i = ORD[q][0];
        const int ox = ORD[q][1];
        const int u = i + ox - 1;   // -1..4, compile-time after unroll
        const float wx  = (u < 0) ? lo[0] : ((u > 3) ? hi[0] : f4c(Rf[0], u));
        const float wy  = (u < 0) ? lo[1] : ((u > 3) ? hi[1] : f4c(Rf[1], u));
        const float wz  = (u < 0) ? lo[2] : ((u > 3) ? hi[2] : f4c(Rf[2], u));
        const float wvx = (u < 0) ? lo[3] : ((u > 3) ? hi[3] : f4c(Rf[3], u));
        const float wvy = (u < 0) ? lo[4] : ((u > 3) ? hi[4] : f4c(Rf[4], u));
        const float wvz = (u < 0) ? lo[5] : ((u > 3) ? hi[5] : f4c(Rf[5], u));
        float dx = px[i] - wx;
        float dy = py[i] - wy;
        float dz = pz[i] - wz;
        float d2 = fmaf(dx, dx, fmaf(dy, dy, dz * dz));
        float r = __builtin_amdgcn_rsqf(d2);     // d2=0 -> inf -> clamped below
        float inv = fminf(r, 1.0e4f);            // = 1/max(dist, 1e-4)
        float inv2 = inv * inv;
        float dvx = vx[i] - wvx;
        float dvy = vy[i] - wvy;
        float dvz = vz[i] - wvz;
        float dvnr = fmaf(dvx, dx, fmaf(dvy, dy, dvz * dz));
        float coef = fmaf(ETAc, dvnr * inv2, fmaf(NKNPS, inv, KNc));
        coef = (d2 < PS2) ? coef : 0.0f;
        fx[i] = fmaf(coef, dx, fx[i]);
        fy[i] = fmaf(coef, dy, fy[i]);
        fz[i] = fmaf(coef, dz, fz[i]);
      }
    };

    // row j in [0,4): grid row y0 + j - 1. j!=3 -> feeds centre row 0; j!=0 -> centre row 1.
    auto compute_row = [&](const float4 (&Rf)[6], int j) {
      float lo[6], hi[6];
#pragma unroll
      for (int f = 0; f < 6; ++f) {
        lo[f] = __shfl(Rf[f].w, laneL, 64);
        hi[f] = __shfl(Rf[f].x, laneR, 64);
      }
      if (j != 3) interact4(Rf, lo, hi, px0, py0, pz0, vx0, vy0, vz0, fx0, fy0, fz0);
      if (j != 0) interact4(Rf, lo, hi, px1, py1, pz1, vx1, vy1, vz1, fx1, fy1, fz1);
    };

    auto rowbase = [&](int k) -> int {   // k in [0,12): oz = k>>2, j = k&3
      const int zr = (z + (k >> 2) + DM) & DM;
      const int yr = (y0 + (k & 3) + DM) & DM;
      return (zr * DD + yr) * DD + x0;
    };

    float4 A[6], B[6];
    {
      const int rb0 = rowbase(0);
#pragma unroll
      for (int f = 0; f < 6; ++f) A[f] = *(const float4*)(Q0[f] + rb0);
    }

#pragma unroll 1
    for (int k = 0; k < 12; ++k) {
      const int j = k & 3;
      const int rb = rowbase(k);
#pragma unroll
      for (int f = 0; f < 6; ++f) B[f] = *(const float4*)(Q1[f] + rb);
      compute_row(A, j);                       // layer-0 row k
      const int rb1 = rowbase(k < 11 ? k + 1 : 11);
#pragma unroll
      for (int f = 0; f < 6; ++f) A[f] = *(const float4*)(Q0[f] + rb1);
      compute_row(B, j);                       // layer-1 row k
    }
  } else {
#pragma unroll
    for (int i = 0; i < 4; ++i) {
      collide<2>(x0 + i, y0, z, xg, yg, zg, v0x, v0y, v0z, v1x, v1y, v1z,
                 px0[i], py0[i], pz0[i], vx0[i], vy0[i], vz0[i],
                 fx0[i], fy0[i], fz0[i], cc);
      collide<2>(x0 + i, y0 + 1, z, xg, yg, zg, v0x, v0y, v0z, v1x, v1y, v1z,
                 px1[i], py1[i], pz1[i], vx1[i], vy1[i], vz1[i],
                 fx1[i], fy1[i], fz1[i], cc);
    }
  }

  const float4 mk04 = *(const float4*)(maskn + idx0);   // loaded late:
  const float4 mk14 = *(const float4*)(maskn + idx1);   // out of loop liveness
  float4 ox4, oy4, oz4;
#pragma unroll
  for (int i = 0; i < 4; ++i) {
    const float mkv = f4c(mk04, i);
    const float fxb = bforce(px0[i], vx0[i], mkv, cc);
    const float fyb = bforce(py0[i], vy0[i], mkv, cc);
    const float fzb = bforce(pz0[i], vz0[i], mkv, cc);
    const float s = cc.dtpm * mkv;
    (&ox4.x)[i] = vx0[i] + s * (fxb - fx0[i]);
    (&oy4.x)[i] = vy0[i] + s * (fyb - fy0[i]);
    (&oz4.x)[i] = vz0[i] + s * ((cc.grav - fz0[i]) + fzb);
  }
  *(float4*)(outx + idx0) = ox4;
  *(float4*)(outy + idx0) = oy4;
  *(float4*)(outz + idx0) = oz4;
#pragma unroll
  for (int i = 0; i < 4; ++i) {
    const float mkv = f4c(mk14, i);
    const float fxb = bforce(px1[i], vx1[i], mkv, cc);
    const float fyb = bforce(py1[i], vy1[i], mkv, cc);
    const float fzb = bforce(pz1[i], vz1[i], mkv, cc);
    const float s = cc.dtpm * mkv;
    (&ox4.x)[i] = vx1[i] + s * (fxb - fx1[i]);
    (&oy4.x)[i] = vy1[i] + s * (fyb - fy1[i]);
    (&oz4.x)[i] = vz1[i] + s * ((cc.grav - fz1[i]) + fzb);
  }
  *(float4*)(outx + idx1) = ox4;
  *(float4*)(outy + idx1) = oy4;
  *(float4*)(outz + idx1) = oz4;
}

}  // namespace

extern "C" void kernel_launch(void* const* d_in, const int* in_sizes, int n_in,
                              void* d_out, int out_size, void* d_ws, size_t ws_size,
                              hipStream_t stream) {
  const float* xg = (const float*)d_in[0];
  const float* yg = (const float*)d_in[1];
  const float* zg = (const float*)d_in[2];
  const float* vx = (const float*)d_in[3];
  const float* vy = (const float*)d_in[4];
  const float* vz = (const float*)d_in[5];
  const float* mk = (const float*)d_in[6];
  float* out = (float*)d_out;
  unsigned* flag = (unsigned*)d_ws;

  const double PSd = 0.1, CELLd = 0.1, KNd = 6.0e6;
  const double ALPHA = -log(0.5) / 3.141592653589793;
  const double GAMMA = ALPHA / sqrt(ALPHA * ALPHA + 1.0);
  const double PMd = 4.0 / 3.0 * 3.1415 * (0.1 * 0.1 * 0.1) * 2700.0;
  const double ETAd = 2.0 * GAMMA * sqrt(KNd * PMd);

  Consts cc;
  cc.kn = (float)KNd;
  cc.ps = (float)PSd;
  cc.eta = (float)ETAd;
  cc.dtpm = (float)(1e-4 / PMd);
  cc.grav = (float)(-9.8 * PMd);
  cc.lo_hi = (float)(1.5 * PSd);
  cc.hi_th = (float)(DD * CELLd - 0.5 * PSd - CELLd);
  cc.dcell = (float)(DD * CELLd);
  cc.cell = (float)CELLd;
  cc.hps = (float)(0.5 * PSd);
  cc.ps2 = cc.ps * cc.ps;
  cc.nknps = -(cc.kn * cc.ps);

  hipMemsetAsync(d_ws, 0, sizeof(unsigned), stream);
  checker<<<(2 * D3) / 256, 256, 0, stream>>>(xg, yg, zg, flag, cc.cell);

  dim3 blk(256, 1, 1), grd(1024, 1, 1);
  // Pass n=0: neighbor velocities = original inputs (both layers); own = input layer 0.
  dem_pass<<<grd, blk, 0, stream>>>(
      0, xg, yg, zg,
      vx, vy, vz,
      vx + D3, vy + D3, vz + D3,
      vx, vy, vz,
      mk,
      out, out + 2 * D3, out + 4 * D3,
      flag, cc);
  // Pass n=1: m=0 source is the UPDATED layer 0 (just written to out).
  dem_pass<<<grd, blk, 0, stream>>>(
      1, xg, yg, zg,
      out, out + 2 * D3, out + 4 * D3,
      vx + D3, vy + D3, vz + D3,
      vx + D3, vy + D3, vz + D3,
      mk + D3,
      out + D3, out + 3 * D3, out + 5 * D3,
      flag, cc);
}